// Round 1
// baseline (338.730 us; speedup 1.0000x reference)
//
#include <hip/hip_runtime.h>
#include <math.h>

#define DIM    512
#define HEADS  8
#define DK     32
#define NKEYS  256
#define PKTOP  16
#define NTOK   1024   // b*n = 2*512

// gelu (tanh approx, matches flax approximate gelu)
__device__ __forceinline__ float gelu_t(float x)
{
    float x3 = x * x * x;
    return 0.5f * x * (1.f + tanhf(0.7978845608028654f * (x + 0.044715f * x3)));
}

// ---------------- 1-wave fp32 GEMM, 32x32 tile, 4x4 per lane ----------------
// A: [M,K] row-major. B: [K,N] row-major (BT=false) or [N,K] row-major (BT=true).
// EPI==0: C = scale*acc.  EPI==1: C = gelu(acc) * WS[m][n]  (WS is [M,N] rm).
// ZW: block additionally zeroes 512 floats of WS at offset bid*512 (wsum init).
// Layout: lane = mg*8+ng (mg,ng in 0..7); lane owns C[m0+mg*4+i][n0+ng*4+j].
// Inner loop: 2x ds_read_b128 (both conflict-free broadcasts) per 16 FMA.
template<bool BT, int EPI, bool ZW>
__global__ __launch_bounds__(64)
void wgemm(const float* __restrict__ A, const float* __restrict__ B,
           float* __restrict__ C, int M, int N, int K, float scale,
           float* __restrict__ WS)
{
    __shared__ float As[64][36];   // [k][m], stride 36 floats = 144 B (16B-aligned)
    __shared__ float Bs[64][36];   // [k][n]
    const int lane = threadIdx.x;
    const int mg   = lane >> 3;    // 0..7
    const int ng   = lane & 7;     // 0..7
    const int m0   = blockIdx.y * 32;
    const int n0   = blockIdx.x * 32;

    if (ZW) {
        const int bid = blockIdx.y * gridDim.x + blockIdx.x;
        float4 z = make_float4(0.f, 0.f, 0.f, 0.f);
        *(float4*)(WS + (size_t)bid * 512 + lane * 8)     = z;
        *(float4*)(WS + (size_t)bid * 512 + lane * 8 + 4) = z;
    }

    const int r16 = lane >> 4;     // 0..3
    const int c16 = lane & 15;     // 0..15
    const int r8  = lane >> 3;     // 0..7
    const int c8  = lane & 7;      // 0..7

    float acc[4][4] = {{0.f}};

    for (int k0 = 0; k0 < K; k0 += 64) {
        // A tile: rows m0..+31, cols k0..+63 -> As[k][m] (transposed store)
#pragma unroll
        for (int it = 0; it < 8; ++it) {
            int row  = r16 + 4 * it;
            float4 v = *(const float4*)(A + (size_t)(m0 + row) * K + k0 + c16 * 4);
            As[c16 * 4 + 0][row] = v.x; As[c16 * 4 + 1][row] = v.y;
            As[c16 * 4 + 2][row] = v.z; As[c16 * 4 + 3][row] = v.w;
        }
        if (!BT) {
            // B tile: rows k0..+63, cols n0..+31 -> Bs[k][n] (natural store)
#pragma unroll
            for (int it = 0; it < 8; ++it) {
                int kr   = r8 + 8 * it;
                float4 v = *(const float4*)(B + (size_t)(k0 + kr) * N + n0 + c8 * 4);
                *(float4*)&Bs[kr][c8 * 4] = v;
            }
        } else {
            // B tile: rows n0..+31 of [N,K], cols k0..+63 -> Bs[k][n] (transposed)
#pragma unroll
            for (int it = 0; it < 8; ++it) {
                int nr   = r16 + 4 * it;
                float4 v = *(const float4*)(B + (size_t)(n0 + nr) * K + k0 + c16 * 4);
                Bs[c16 * 4 + 0][nr] = v.x; Bs[c16 * 4 + 1][nr] = v.y;
                Bs[c16 * 4 + 2][nr] = v.z; Bs[c16 * 4 + 3][nr] = v.w;
            }
        }
        __syncthreads();
#pragma unroll
        for (int k = 0; k < 64; ++k) {
            float4 a = *(const float4*)&As[k][mg * 4];   // 8-lane broadcast, all banks
            float4 b = *(const float4*)&Bs[k][ng * 4];
            float af[4] = {a.x, a.y, a.z, a.w};
            float bf[4] = {b.x, b.y, b.z, b.w};
#pragma unroll
            for (int i = 0; i < 4; ++i)
#pragma unroll
                for (int j = 0; j < 4; ++j) acc[i][j] += af[i] * bf[j];
        }
        __syncthreads();
    }

#pragma unroll
    for (int i = 0; i < 4; ++i) {
        int m = m0 + mg * 4 + i;
        float4 o;
        if (EPI == 1) {
            float4 w = *(const float4*)(WS + (size_t)m * N + n0 + ng * 4);
            o.x = gelu_t(acc[i][0]) * w.x;
            o.y = gelu_t(acc[i][1]) * w.y;
            o.z = gelu_t(acc[i][2]) * w.z;
            o.w = gelu_t(acc[i][3]) * w.w;
        } else {
            o = make_float4(acc[i][0] * scale, acc[i][1] * scale,
                            acc[i][2] * scale, acc[i][3] * scale);
        }
        *(float4*)(C + (size_t)m * N + n0 + ng * 4) = o;
    }
}

// ---------------- sim + double top-16 + softmax -> atomic wsum --------------
// Wave-wide argmax with lax.top_k tie semantics: max value; on tie, lowest
// flat index wins. Flat index = lane*4 + slot. Instead of writing pk/wt,
// the softmax weight is atomically accumulated into wsum[token][expert]
// (wsum pre-zeroed by the q-GEMM kernel). This kills the 8x-redundant
// scatter pass in the down-projection kernel entirely.
__global__ __launch_bounds__(256)
void k_simtopk(const float* __restrict__ q, const float* __restrict__ keys,
               float* __restrict__ wsum)
{
    const int lane = threadIdx.x & 63;
    const int th   = blockIdx.x * 4 + (threadIdx.x >> 6);   // token-head 0..8191
    const int t    = th >> 3;
    const int hh   = th & 7;
    const int base = lane * 4;

    // wave-uniform q sub-row (p=0 half): cols hh*32 .. hh*32+31
    const float4* qv = (const float4*)(q + (size_t)t * DIM + hh * DK);
    float4 qr[8];
#pragma unroll
    for (int i = 0; i < 8; ++i) qr[i] = qv[i];

    // 4 keys per lane: k = base + j ;  keys[h][k][0][d]
    float v1[4];
#pragma unroll
    for (int j = 0; j < 4; ++j) {
        int k = base + j;
        const float4* kv = (const float4*)(keys + ((size_t)hh * NKEYS + k) * 2 * DK);
        float s = 0.f;
#pragma unroll
        for (int i = 0; i < 8; ++i) {
            float4 kk = kv[i];
            s += kk.x * qr[i].x + kk.y * qr[i].y + kk.z * qr[i].z + kk.w * qr[i].w;
        }
        v1[j] = s;
    }

    // stage 1: top-16 of sim. Per-lane captures for stage 2:
    //   lane l needs v0[l>>2] and i0[4*(l&3)+jj], jj=0..3
    float my_v0 = 0.f;
    int   my_i0[4] = {0, 0, 0, 0};
#pragma unroll
    for (int r = 0; r < 16; ++r) {
        float b = v1[0]; int bj = 0;
        if (v1[1] > b) { b = v1[1]; bj = 1; }
        if (v1[2] > b) { b = v1[2]; bj = 2; }
        if (v1[3] > b) { b = v1[3]; bj = 3; }
        float m = b;
#pragma unroll
        for (int off = 32; off; off >>= 1) m = fmaxf(m, __shfl_xor(m, off, 64));
        unsigned long long bal = __ballot(b == m);
        int wl   = __ffsll((long long)bal) - 1;
        int widx = __shfl(base + bj, wl, 64);
        if ((lane >> 2) == r)       my_v0        = m;
        if ((lane & 3) == (r >> 2)) my_i0[r & 3] = widx;
        if (lane == wl) v1[bj] = -INFINITY;
    }

    // stage 2: candidate c = base+jj == 16*i + j with i=c>>4, j=c&15
    float v2[4];
#pragma unroll
    for (int jj = 0; jj < 4; ++jj) v2[jj] = my_v0 + (float)my_i0[jj];

    float sc0 = 0.f, ssum = 0.f, my_sc = 0.f;
    int   my_pk = 0;
#pragma unroll
    for (int r = 0; r < 16; ++r) {
        float b = v2[0]; int bj = 0;
        if (v2[1] > b) { b = v2[1]; bj = 1; }
        if (v2[2] > b) { b = v2[2]; bj = 2; }
        if (v2[3] > b) { b = v2[3]; bj = 3; }
        float m = b;
#pragma unroll
        for (int off = 32; off; off >>= 1) m = fmaxf(m, __shfl_xor(m, off, 64));
        unsigned long long bal = __ballot(b == m);
        int wl = __ffsll((long long)bal) - 1;
        int wc = __shfl(base + bj, wl, 64);
        if (r == 0) sc0 = m;              // round-0 winner is the max
        ssum += expf(m - sc0);
        if (lane == r) { my_sc = m; my_pk = wc; }
        if (lane == wl) v2[bj] = -INFINITY;
    }
    if (lane < PKTOP)
        atomicAdd(&wsum[(size_t)t * NKEYS + my_pk], expf(my_sc - sc0) / ssum);
}

// ---------------- launch ----------------
extern "C" void kernel_launch(void* const* d_in, const int* in_sizes, int n_in,
                              void* d_out, int out_size, void* d_ws, size_t ws_size,
                              hipStream_t stream)
{
    const float* x    = (const float*)d_in[0];   // [1024, 512]
    const float* wq   = (const float*)d_in[1];   // [512, 512]
    const float* keys = (const float*)d_in[2];   // [8, 256, 2, 32]
    const float* wd   = (const float*)d_in[3];   // [65536, 512] (rows 0..255 used)
    const float* wu   = (const float*)d_in[4];   // [65536, 512] (rows 0..255 used)
    float* out = (float*)d_out;                  // [1024, 512]

    float* q    = (float*)d_ws;                  // 1024*512
    float* Cb   = q + NTOK * DIM;                // 1024*256
    float* wsum = Cb + NTOK * NKEYS;             // 1024*256

    const float bnscale = 1.0f / sqrtf(1.0f + 1e-5f);

    // q = (x @ wq) * bnscale  [1024 x 512], K=512; also zeroes wsum (512 f/block)
    wgemm<false, 0, true>
        <<<dim3(DIM / 32, NTOK / 32), 64, 0, stream>>>(x, wq, q, NTOK, DIM, DIM,
                                                       bnscale, wsum);

    // sim + double top-16 + softmax -> atomic accumulate into wsum[t][e]
    k_simtopk<<<dim3(NTOK * HEADS / 4), 256, 0, stream>>>(q, keys, wsum);

    // Cb[t,e] = gelu(q . wd[e]) * wsum[t,e]   [1024 x 256], K=512, B transposed
    wgemm<true, 1, false>
        <<<dim3(NKEYS / 32, NTOK / 32), 64, 0, stream>>>(q, wd, Cb, NTOK, NKEYS,
                                                         DIM, 1.f, wsum);

    // out = Cb @ wu[0:256]   [1024 x 512], K=256
    wgemm<false, 0, false>
        <<<dim3(DIM / 32, NTOK / 32), 64, 0, stream>>>(Cb, wu, out, NTOK, DIM,
                                                       NKEYS, 1.f, (float*)nullptr);
}